// Round 6
// baseline (1298.121 us; speedup 1.0000x reference)
//
#include <hip/hip_runtime.h>
#include <math.h>

// AnyNet stereo forward, fp32. Round 6: LDS weights (broadcast reads are free)
// + explicit 2-deep register pipeline across input channels (issue ci+1 loads
// before ci FMAs) + WT=2 on stage0/1 for >=480 blocks (TLP). Padded
// activations (branch-free taps) kept from R4.

#define FULL_H 512
#define FULL_W 1280
#define NB 8
#define NPIX (NB * FULL_H * FULL_W)   // 5,242,880

// ---------------- stage-0 L1 cost volume -> padded ----------------
__global__ __launch_bounds__(256) void cost0p_k(const float* __restrict__ fl,
                                                const float* __restrict__ fr,
                                                float* __restrict__ costp) {
    const int H = 32, W = 80, D = 12, C = 8;
    const int DZ = 14, HZ = 34, WZ = 88;
    int idx = blockIdx.x * 256 + threadIdx.x;
    int total = NB * D * H * W;
    if (idx >= total) return;
    int w = idx % W; int t = idx / W;
    int h = t % H; t /= H;
    int d = t % D; int b = t / D;
    int src = w - d;
    float acc = 0.f;
    for (int c = 0; c < C; ++c) {
        int base = ((b * C + c) * H + h) * W;
        float flv = fl[base + w];
        float frv = (src >= 0) ? fr[base + src] : 0.f;
        acc += fabsf(flv - frv);
    }
    costp[((b * DZ + (d + 1)) * HZ + (h + 1)) * WZ + (w + 4)] = acc;
}

// ---------------- residual (warped) cost volume -> padded ----------------
__global__ __launch_bounds__(256) void costresp_k(const float* __restrict__ fl,
                                                  const float* __restrict__ fr,
                                                  const float* __restrict__ wf,
                                                  float* __restrict__ costp,
                                                  int H, int W, int HZ, int WZ) {
    const int C = 8, S = 5, DZ = 7;
    int idx = blockIdx.x * 256 + threadIdx.x;
    int total = NB * S * H * W;
    if (idx >= total) return;
    int w = idx % W; int t = idx / W;
    int h = t % H; t /= H;
    int s = t % S; int b = t / S;
    float disp  = wf[(b * H + h) * W + w];
    float shift = (float)(s - 2);
    float xs  = (float)w - (disp - shift);
    float x0f = floorf(xs);
    float w1  = xs - x0f;
    float x0fc = fminf(fmaxf(x0f, -2.f), (float)W);
    int x0 = (int)x0fc;
    int x1 = x0 + 1;
    float m0 = (x0 >= 0 && x0 <= W - 1) ? (1.f - w1) : 0.f;
    float m1 = (x1 >= 0 && x1 <= W - 1) ? w1 : 0.f;
    int x0c = min(max(x0, 0), W - 1);
    int x1c = min(max(x1, 0), W - 1);
    float acc = 0.f;
    const float* flb = fl + ((b * C) * H + h) * W;
    const float* frb = fr + ((b * C) * H + h) * W;
    for (int c = 0; c < C; ++c) {
        float v = frb[x0c] * m0 + frb[x1c] * m1;
        acc += fabsf(flb[w] - v);
        flb += H * W;
        frb += H * W;
    }
    costp[((b * DZ + (s + 1)) * HZ + (h + 1)) * WZ + (w + 4)] = acc;
}

// ---------------- conv helpers ----------------
template <int WT>
__device__ __forceinline__ void load_rows(const float* __restrict__ xc,
                                          int zhs, int WZ,
                                          float* __restrict__ xr /* 9*(WT+2) */) {
#pragma unroll
    for (int kd = 0; kd < 3; ++kd) {
#pragma unroll
        for (int kh = 0; kh < 3; ++kh) {
            const float* row = xc + kd * zhs + kh * WZ;
            float* r = xr + (kd * 3 + kh) * (WT + 2);
            if constexpr (WT % 4 == 0) {
#pragma unroll
                for (int j = 0; j < WT / 4; ++j) {
                    float4 v = *reinterpret_cast<const float4*>(row + j * 4);
                    r[1 + j * 4 + 0] = v.x; r[1 + j * 4 + 1] = v.y;
                    r[1 + j * 4 + 2] = v.z; r[1 + j * 4 + 3] = v.w;
                }
                r[0] = row[-1]; r[WT + 1] = row[WT];
            } else { // WT == 2: 4 scalars (pairs merge to dwordx2 where aligned)
                r[0] = row[-1]; r[1] = row[0]; r[2] = row[1]; r[3] = row[2];
            }
        }
    }
}

template <int COUT, int WT>
__device__ __forceinline__ void fma_ci(const float* __restrict__ xr,
                                       const float* __restrict__ wlc, /* 27*COUT LDS */
                                       float* __restrict__ acc /* COUT*WT */) {
#pragma unroll
    for (int kd = 0; kd < 3; ++kd) {
#pragma unroll
        for (int kh = 0; kh < 3; ++kh) {
            const float* r = xr + (kd * 3 + kh) * (WT + 2);
#pragma unroll
            for (int kw = 0; kw < 3; ++kw) {
                const float* wp = wlc + (kd * 9 + kh * 3 + kw) * COUT;
                if constexpr (COUT == 1) {
                    float wv = wp[0];
#pragma unroll
                    for (int wt = 0; wt < WT; ++wt)
                        acc[wt] = fmaf(r[wt + kw], wv, acc[wt]);
                } else {
                    float4 w4[COUT / 4];
#pragma unroll
                    for (int q = 0; q < COUT / 4; ++q)
                        w4[q] = reinterpret_cast<const float4*>(wp)[q];
#pragma unroll
                    for (int wt = 0; wt < WT; ++wt) {
                        float xv = r[wt + kw];
#pragma unroll
                        for (int q = 0; q < COUT / 4; ++q) {
                            acc[(q * 4 + 0) * WT + wt] = fmaf(xv, w4[q].x, acc[(q * 4 + 0) * WT + wt]);
                            acc[(q * 4 + 1) * WT + wt] = fmaf(xv, w4[q].y, acc[(q * 4 + 1) * WT + wt]);
                            acc[(q * 4 + 2) * WT + wt] = fmaf(xv, w4[q].z, acc[(q * 4 + 2) * WT + wt]);
                            acc[(q * 4 + 3) * WT + wt] = fmaf(xv, w4[q].w, acc[(q * 4 + 3) * WT + wt]);
                        }
                    }
                }
            }
        }
    }
}

// ---------------- padded branch-free 3x3x3 conv3d, ci-pipelined ----------------
// x: padded [B,CIN,DZ,HZ,WZ]; wg: [COUT,CIN,27]; y: padded or unpadded output.
template <int CIN, int COUT, int WT, bool RELU, bool PADOUT>
__global__ __launch_bounds__(256) void convp_k(const float* __restrict__ x,
                                               const float* __restrict__ wg,
                                               float* __restrict__ y,
                                               int D, int H, int W,
                                               int DZ, int HZ, int WZ,
                                               int nstrips) {
    __shared__ __align__(16) float wl[CIN * 27 * COUT];
    for (int i = threadIdx.x; i < CIN * 27 * COUT; i += 256) {
        int co = i % COUT; int rest = i / COUT;
        int tap = rest % 27; int ci = rest / 27;
        wl[i] = wg[(co * CIN + ci) * 27 + tap];
    }
    __syncthreads();

    int idx = blockIdx.x * 256 + threadIdx.x;
    if (idx >= nstrips) return;
    const int SW = W / WT;
    int sw = idx % SW; int t = idx / SW;
    int h = t % H; t /= H;
    int d = t % D; int b = t / D;
    const int wcol = sw * WT + 4;
    const int zhs = HZ * WZ;
    const int zcs = DZ * zhs;

    float acc[COUT * WT];
#pragma unroll
    for (int i = 0; i < COUT * WT; ++i) acc[i] = 0.f;

    const float* xc = x + (size_t)b * CIN * zcs + (size_t)d * zhs + (size_t)h * WZ + wcol;

    float bufA[9 * (WT + 2)];
    float bufB[9 * (WT + 2)];

    if constexpr (CIN == 1) {
        load_rows<WT>(xc, zhs, WZ, bufA);
        fma_ci<COUT, WT>(bufA, wl, acc);
    } else {
        // 2-deep register pipeline over ci (CIN even): issue next-ci loads
        // before current-ci FMAs so L2 latency hides under the FMA block.
        load_rows<WT>(xc, zhs, WZ, bufA);
        for (int ci = 0; ci < CIN; ci += 2) {
            load_rows<WT>(xc + zcs, zhs, WZ, bufB);
            fma_ci<COUT, WT>(bufA, wl + (size_t)ci * 27 * COUT, acc);
            if (ci + 2 < CIN)
                load_rows<WT>(xc + 2 * zcs, zhs, WZ, bufA);
            fma_ci<COUT, WT>(bufB, wl + (size_t)(ci + 1) * 27 * COUT, acc);
            xc += 2 * zcs;
        }
    }

    if constexpr (PADOUT) {
        float* yb = y + (size_t)b * COUT * zcs + (size_t)(d + 1) * zhs + (size_t)(h + 1) * WZ + wcol;
#pragma unroll
        for (int co = 0; co < COUT; ++co) {
#pragma unroll
            for (int wt = 0; wt < WT; ++wt) {
                float v = acc[co * WT + wt];
                if (RELU) v = fmaxf(v, 0.f);
                yb[(size_t)co * zcs + wt] = v;
            }
        }
    } else {
        const int chs = D * H * W;
        float* yb = y + (size_t)b * COUT * chs + (d * H + h) * W + sw * WT;
#pragma unroll
        for (int co = 0; co < COUT; ++co) {
#pragma unroll
            for (int wt = 0; wt < WT; ++wt) {
                float v = acc[co * WT + wt];
                if (RELU) v = fmaxf(v, 0.f);
                yb[(size_t)co * chs + wt] = v;
            }
        }
    }
}

// ---------------- softargmin disparity regression ----------------
__global__ __launch_bounds__(256) void dispreg_k(const float* __restrict__ cost,
                                                 float* __restrict__ dsm,
                                                 int total, int D, int HW,
                                                 float dstart, float scale) {
    int idx = blockIdx.x * 256 + threadIdx.x;
    if (idx >= total) return;
    int hw = idx % HW; int b = idx / HW;
    const float* c = cost + b * D * HW + hw;
    float m = -1e30f;
    for (int d = 0; d < D; ++d) m = fmaxf(m, -c[d * HW]);
    float s = 0.f, ws = 0.f;
    for (int d = 0; d < D; ++d) {
        float e = expf(-c[d * HW] - m);
        s += e;
        ws = fmaf(e, dstart + (float)d, ws);
    }
    dsm[idx] = ws / s * scale;
}

// ---------------- bilinear upsample + optional residual + optional depth ----------------
__global__ __launch_bounds__(256) void upsample_add_k(const float* __restrict__ s,
                                                      int sh, int sw,
                                                      const float* __restrict__ prev,
                                                      float* __restrict__ out,
                                                      float* __restrict__ dep) {
    int idx = blockIdx.x * 256 + threadIdx.x;
    if (idx >= NPIX) return;
    int x = idx % FULL_W; int t = idx / FULL_W;
    int y = t % FULL_H; int b = t / FULL_H;
    float fy = (y + 0.5f) * ((float)sh / FULL_H) - 0.5f;
    float fx = (x + 0.5f) * ((float)sw / FULL_W) - 0.5f;
    int y0 = (int)floorf(fy); float wy = fy - (float)y0;
    int x0 = (int)floorf(fx); float wx = fx - (float)x0;
    int y0c = min(max(y0, 0), sh - 1), y1c = min(max(y0 + 1, 0), sh - 1);
    int x0c = min(max(x0, 0), sw - 1), x1c = min(max(x0 + 1, 0), sw - 1);
    const float* sb = s + b * sh * sw;
    float v00 = sb[y0c * sw + x0c], v01 = sb[y0c * sw + x1c];
    float v10 = sb[y1c * sw + x0c], v11 = sb[y1c * sw + x1c];
    float v = (1.f - wy) * ((1.f - wx) * v00 + wx * v01) +
              wy        * ((1.f - wx) * v10 + wx * v11);
    if (prev) v += prev[idx];
    out[idx] = v;
    if (dep) {
        float p = fabsf(v);
        float d = 64.f / p;                 // BASELINE*FOCAL
        if (isnan(d)) d = 100.f;
        d = fminf(fmaxf(d, 0.1f), 100.f);
        dep[idx] = d;
    }
}

// ---------------- antialiased triangle downsample + scale ----------------
__global__ __launch_bounds__(256) void wflow_k(const float* __restrict__ pred,
                                               float* __restrict__ wf,
                                               int oh, int ow, int f, float scale) {
    int idx = blockIdx.x * 256 + threadIdx.x;
    int total = NB * oh * ow;
    if (idx >= total) return;
    int ox = idx % ow; int t = idx / ow;
    int oy = t % oh; int b = t / oh;
    float ff = (float)f, invf = 1.f / (float)f;
    float cy = (oy + 0.5f) * ff - 0.5f;
    float cx = (ox + 0.5f) * ff - 0.5f;
    int ylo = max((int)ceilf(cy - ff), 0);
    int yhi = min((int)floorf(cy + ff), FULL_H - 1);
    int xlo = max((int)ceilf(cx - ff), 0);
    int xhi = min((int)floorf(cx + ff), FULL_W - 1);
    const float* pb = pred + b * FULL_H * FULL_W;
    float acc = 0.f, wys = 0.f, wxs = 0.f;
    for (int iy = ylo; iy <= yhi; ++iy) {
        float wy = 1.f - fabsf((float)iy - cy) * invf;
        wys += wy;
        float rowacc = 0.f;
        const float* row = pb + iy * FULL_W;
        for (int ix = xlo; ix <= xhi; ++ix) {
            float wx = 1.f - fabsf((float)ix - cx) * invf;
            rowacc = fmaf(wx, row[ix], rowacc);
        }
        acc = fmaf(wy, rowacc, acc);
    }
    for (int ix = xlo; ix <= xhi; ++ix) wxs += 1.f - fabsf((float)ix - cx) * invf;
    wf[idx] = acc / (wys * wxs) * scale;
}

static inline dim3 g(int n) { return dim3((n + 255) / 256); }

extern "C" void kernel_launch(void* const* d_in, const int* in_sizes, int n_in,
                              void* d_out, int out_size, void* d_ws, size_t ws_size,
                              hipStream_t stream) {
    const float* f_l0  = (const float*)d_in[0];
    const float* f_r0  = (const float*)d_in[1];
    const float* f_l1  = (const float*)d_in[2];
    const float* f_r1  = (const float*)d_in[3];
    const float* f_l2  = (const float*)d_in[4];
    const float* f_r2  = (const float*)d_in[5];
    const float* w_in0  = (const float*)d_in[6];
    const float* w_mid0 = (const float*)d_in[7];
    const float* w_out0 = (const float*)d_in[8];
    const float* w_in1  = (const float*)d_in[9];
    const float* w_mid1 = (const float*)d_in[10];
    const float* w_out1 = (const float*)d_in[11];
    const float* w_in2  = (const float*)d_in[12];
    const float* w_mid2 = (const float*)d_in[13];
    const float* w_out2 = (const float*)d_in[14];

    float* out   = (float*)d_out;
    float* pred0 = out;
    float* pred1 = out + NPIX;
    float* pred2 = out + 2 * NPIX;
    float* depth = out + 3 * NPIX;

    float* ws = (float*)d_ws;
    float* P    = ws;               // padded ping (max 9,551,360 floats)
    float* Q    = ws + 9551360;     // padded pong
    float* CP   = ws + 19102720;    // padded cost input (max 2,387,840)
    float* CO   = ws + 21490560;    // unpadded conv output (max 1,638,400)
    float* dsm  = ws + 23128960;    // 327,680
    float* wfl  = ws + 23456640;    // 327,680  (end ~95.1 MB)

    dim3 blk(256);

    // ---------------- stage 0 ----------------
    {
        const int D = 12, H = 32, W = 80, DZ = 14, HZ = 34, WZ = 88;
        const size_t pcn = (size_t)NB * 16 * DZ * HZ * WZ;   // 5,361,664
        const size_t cpn = (size_t)NB * DZ * HZ * WZ;        //   335,104
        hipMemsetAsync(P,  0, pcn * 4, stream);
        hipMemsetAsync(Q,  0, pcn * 4, stream);
        hipMemsetAsync(CP, 0, cpn * 4, stream);
        const int total = NB * D * H * W;                    // 245,760
        cost0p_k<<<g(total), blk, 0, stream>>>(f_l0, f_r0, CP);
        int ns2 = total / 2;                                 // 122,880 -> 480 blocks
        int ns4 = total / 4;                                 //  61,440 -> 240 blocks
        convp_k<1, 16, 2, true, true><<<g(ns2), blk, 0, stream>>>(CP, w_in0, P, D, H, W, DZ, HZ, WZ, ns2);
        const float* src = P; float* dst = Q;
        for (int k = 0; k < 4; ++k) {
            convp_k<16, 16, 2, true, true><<<g(ns2), blk, 0, stream>>>(src, w_mid0 + k * 6912, dst, D, H, W, DZ, HZ, WZ, ns2);
            const float* nsrc = dst; dst = (float*)src; src = nsrc;
        }
        convp_k<16, 1, 4, false, false><<<g(ns4), blk, 0, stream>>>(src, w_out0, CO, D, H, W, DZ, HZ, WZ, ns4);
        dispreg_k<<<g(NB * H * W), blk, 0, stream>>>(CO, dsm, NB * H * W, D, H * W, 0.f, 16.f);
        upsample_add_k<<<g(NPIX), blk, 0, stream>>>(dsm, H, W, nullptr, pred0, depth);
    }

    // ---------------- stage 1 ----------------
    {
        const int D = 5, H = 64, W = 160, DZ = 7, HZ = 66, WZ = 168;
        const size_t pcn = (size_t)NB * 4 * DZ * HZ * WZ;    // 2,483,712
        const size_t cpn = (size_t)NB * DZ * HZ * WZ;        //   620,928
        hipMemsetAsync(P,  0, pcn * 4, stream);
        hipMemsetAsync(Q,  0, pcn * 4, stream);
        hipMemsetAsync(CP, 0, cpn * 4, stream);
        const int total = NB * D * H * W;                    // 409,600
        wflow_k<<<g(NB * H * W), blk, 0, stream>>>(pred0, wfl, H, W, 8, 0.125f);
        costresp_k<<<g(total), blk, 0, stream>>>(f_l1, f_r1, wfl, CP, H, W, HZ, WZ);
        int ns2 = total / 2;                                 // 204,800 -> 800 blocks
        int ns4 = total / 4;                                 // 102,400 -> 400 blocks
        convp_k<1, 4, 2, true, true><<<g(ns2), blk, 0, stream>>>(CP, w_in1, P, D, H, W, DZ, HZ, WZ, ns2);
        const float* src = P; float* dst = Q;
        for (int k = 0; k < 4; ++k) {
            convp_k<4, 4, 2, true, true><<<g(ns2), blk, 0, stream>>>(src, w_mid1 + k * 432, dst, D, H, W, DZ, HZ, WZ, ns2);
            const float* nsrc = dst; dst = (float*)src; src = nsrc;
        }
        convp_k<4, 1, 4, false, false><<<g(ns4), blk, 0, stream>>>(src, w_out1, CO, D, H, W, DZ, HZ, WZ, ns4);
        dispreg_k<<<g(NB * H * W), blk, 0, stream>>>(CO, dsm, NB * H * W, D, H * W, -2.f, 8.f);
        upsample_add_k<<<g(NPIX), blk, 0, stream>>>(dsm, H, W, pred0, pred1, nullptr);
    }

    // ---------------- stage 2 ----------------
    {
        const int D = 5, H = 128, W = 320, DZ = 7, HZ = 130, WZ = 328;
        const size_t pcn = (size_t)NB * 4 * DZ * HZ * WZ;    // 9,551,360
        const size_t cpn = (size_t)NB * DZ * HZ * WZ;        // 2,387,840
        hipMemsetAsync(P,  0, pcn * 4, stream);
        hipMemsetAsync(Q,  0, pcn * 4, stream);
        hipMemsetAsync(CP, 0, cpn * 4, stream);
        const int total = NB * D * H * W;                    // 1,638,400
        wflow_k<<<g(NB * H * W), blk, 0, stream>>>(pred1, wfl, H, W, 4, 0.25f);
        costresp_k<<<g(total), blk, 0, stream>>>(f_l2, f_r2, wfl, CP, H, W, HZ, WZ);
        int ns4 = total / 4;                                 // 409,600 -> 1600 blocks
        convp_k<1, 4, 4, true, true><<<g(ns4), blk, 0, stream>>>(CP, w_in2, P, D, H, W, DZ, HZ, WZ, ns4);
        const float* src = P; float* dst = Q;
        for (int k = 0; k < 4; ++k) {
            convp_k<4, 4, 4, true, true><<<g(ns4), blk, 0, stream>>>(src, w_mid2 + k * 432, dst, D, H, W, DZ, HZ, WZ, ns4);
            const float* nsrc = dst; dst = (float*)src; src = nsrc;
        }
        convp_k<4, 1, 4, false, false><<<g(ns4), blk, 0, stream>>>(src, w_out2, CO, D, H, W, DZ, HZ, WZ, ns4);
        dispreg_k<<<g(NB * H * W), blk, 0, stream>>>(CO, dsm, NB * H * W, D, H * W, -2.f, 4.f);
        upsample_add_k<<<g(NPIX), blk, 0, stream>>>(dsm, H, W, pred1, pred2, nullptr);
    }
}

// Round 7
// 981.897 us; speedup vs baseline: 1.3221x; 1.3221x over previous
//
#include <hip/hip_runtime.h>
#include <math.h>

// AnyNet stereo forward, fp32. Round 7: spill-safe ci-pipelined conv
// (macro-inlined double buffer A/B, constant indices only), LDS weights,
// padded branch-free taps, WT=4, COUT-split 2x on stage-0 mids for regs+TLP.

#define FULL_H 512
#define FULL_W 1280
#define NB 8
#define NPIX (NB * FULL_H * FULL_W)   // 5,242,880

// ---------------- stage-0 L1 cost volume -> padded ----------------
__global__ __launch_bounds__(256) void cost0p_k(const float* __restrict__ fl,
                                                const float* __restrict__ fr,
                                                float* __restrict__ costp) {
    const int H = 32, W = 80, D = 12, C = 8;
    const int DZ = 14, HZ = 34, WZ = 88;
    int idx = blockIdx.x * 256 + threadIdx.x;
    int total = NB * D * H * W;
    if (idx >= total) return;
    int w = idx % W; int t = idx / W;
    int h = t % H; t /= H;
    int d = t % D; int b = t / D;
    int src = w - d;
    float acc = 0.f;
    for (int c = 0; c < C; ++c) {
        int base = ((b * C + c) * H + h) * W;
        float flv = fl[base + w];
        float frv = (src >= 0) ? fr[base + src] : 0.f;
        acc += fabsf(flv - frv);
    }
    costp[((b * DZ + (d + 1)) * HZ + (h + 1)) * WZ + (w + 4)] = acc;
}

// ---------------- residual (warped) cost volume -> padded ----------------
__global__ __launch_bounds__(256) void costresp_k(const float* __restrict__ fl,
                                                  const float* __restrict__ fr,
                                                  const float* __restrict__ wf,
                                                  float* __restrict__ costp,
                                                  int H, int W, int HZ, int WZ) {
    const int C = 8, S = 5, DZ = 7;
    int idx = blockIdx.x * 256 + threadIdx.x;
    int total = NB * S * H * W;
    if (idx >= total) return;
    int w = idx % W; int t = idx / W;
    int h = t % H; t /= H;
    int s = t % S; int b = t / S;
    float disp  = wf[(b * H + h) * W + w];
    float shift = (float)(s - 2);
    float xs  = (float)w - (disp - shift);
    float x0f = floorf(xs);
    float w1  = xs - x0f;
    float x0fc = fminf(fmaxf(x0f, -2.f), (float)W);
    int x0 = (int)x0fc;
    int x1 = x0 + 1;
    float m0 = (x0 >= 0 && x0 <= W - 1) ? (1.f - w1) : 0.f;
    float m1 = (x1 >= 0 && x1 <= W - 1) ? w1 : 0.f;
    int x0c = min(max(x0, 0), W - 1);
    int x1c = min(max(x1, 0), W - 1);
    float acc = 0.f;
    const float* flb = fl + ((b * C) * H + h) * W;
    const float* frb = fr + ((b * C) * H + h) * W;
    for (int c = 0; c < C; ++c) {
        float v = frb[x0c] * m0 + frb[x1c] * m1;
        acc += fabsf(flb[w] - v);
        flb += H * W;
        frb += H * W;
    }
    costp[((b * DZ + (s + 1)) * HZ + (h + 1)) * WZ + (w + 4)] = acc;
}

// ---------------- ci-pipelined padded 3x3x3 conv3d, WT=4 ----------------
// x: padded [B,CIN,DZ,HZ,WZ]; wg: [COUTT,CIN,27]; grid = nblocks*NSPL.
// Each thread: 4 consecutive w outputs x COUTS channels of group cog.
template <int CIN, int COUTT, int COUTS, bool RELU, bool PADOUT>
__global__ __launch_bounds__(256) void convp4_k(const float* __restrict__ x,
                                                const float* __restrict__ wg,
                                                float* __restrict__ y,
                                                int D, int H, int W,
                                                int DZ, int HZ, int WZ,
                                                int nstrips) {
    constexpr int NSPL = COUTT / COUTS;
    int cog, bid;
    if constexpr (NSPL > 1) { cog = blockIdx.x % NSPL; bid = blockIdx.x / NSPL; }
    else { cog = 0; bid = blockIdx.x; }

    __shared__ __align__(16) float wl[CIN * 27 * COUTS];
    for (int i = threadIdx.x; i < CIN * 27 * COUTS; i += 256) {
        int co = i % COUTS; int rest = i / COUTS;
        int tap = rest % 27; int ci = rest / 27;
        wl[i] = wg[((cog * COUTS + co) * CIN + ci) * 27 + tap];
    }
    __syncthreads();

    int idx = bid * 256 + threadIdx.x;
    if (idx >= nstrips) return;
    const int SW = W / 4;
    int sw = idx % SW; int t = idx / SW;
    int h = t % H; t /= H;
    int d = t % D; int b = t / D;
    const int wcol = sw * 4 + 4;           // 4-aligned padded column
    const int zhs = HZ * WZ;
    const int zcs = DZ * zhs;

    float acc[COUTS][4];
#pragma unroll
    for (int co = 0; co < COUTS; ++co)
#pragma unroll
        for (int wt = 0; wt < 4; ++wt) acc[co][wt] = 0.f;

    const float* xb = x + (size_t)b * CIN * zcs + (size_t)d * zhs + (size_t)h * WZ + wcol;

    // row registers: [9 rows][6 floats: wcol-1 .. wcol+4]
    float A[9][6];

#define LOADCI(BUF, CIDX) do {                                                \
    const float* xc_ = xb + (size_t)(CIDX) * zcs;                             \
    _Pragma("unroll")                                                         \
    for (int r_ = 0; r_ < 9; ++r_) {                                          \
        const float* row_ = xc_ + (r_ / 3) * zhs + (r_ % 3) * WZ;             \
        float4 m_ = *reinterpret_cast<const float4*>(row_);                   \
        BUF[r_][0] = row_[-1];                                                \
        BUF[r_][1] = m_.x; BUF[r_][2] = m_.y;                                 \
        BUF[r_][3] = m_.z; BUF[r_][4] = m_.w;                                 \
        BUF[r_][5] = row_[4];                                                 \
    } } while (0)

#define FMACI(BUF, CIDX) do {                                                 \
    const float* wc_ = wl + (size_t)(CIDX) * 27 * COUTS;                      \
    _Pragma("unroll")                                                         \
    for (int r_ = 0; r_ < 9; ++r_) {                                          \
        _Pragma("unroll")                                                     \
        for (int kw_ = 0; kw_ < 3; ++kw_) {                                   \
            const float* wp_ = wc_ + (r_ * 3 + kw_) * COUTS;                  \
            if constexpr (COUTS == 1) {                                       \
                float wv_ = wp_[0];                                           \
                _Pragma("unroll")                                             \
                for (int wt_ = 0; wt_ < 4; ++wt_)                             \
                    acc[0][wt_] = fmaf(BUF[r_][wt_ + kw_], wv_, acc[0][wt_]); \
            } else {                                                          \
                _Pragma("unroll")                                             \
                for (int q_ = 0; q_ < COUTS / 4; ++q_) {                      \
                    float4 w4_ = reinterpret_cast<const float4*>(wp_)[q_];    \
                    _Pragma("unroll")                                         \
                    for (int wt_ = 0; wt_ < 4; ++wt_) {                       \
                        float xv_ = BUF[r_][wt_ + kw_];                       \
                        acc[q_ * 4 + 0][wt_] = fmaf(xv_, w4_.x, acc[q_ * 4 + 0][wt_]); \
                        acc[q_ * 4 + 1][wt_] = fmaf(xv_, w4_.y, acc[q_ * 4 + 1][wt_]); \
                        acc[q_ * 4 + 2][wt_] = fmaf(xv_, w4_.z, acc[q_ * 4 + 2][wt_]); \
                        acc[q_ * 4 + 3][wt_] = fmaf(xv_, w4_.w, acc[q_ * 4 + 3][wt_]); \
                    }                                                         \
                }                                                             \
            }                                                                 \
        }                                                                     \
    } } while (0)

    if constexpr (CIN == 1) {
        LOADCI(A, 0);
        FMACI(A, 0);
    } else {
        float B[9][6];
        LOADCI(A, 0);
        for (int ci = 0; ci < CIN; ci += 2) {   // CIN even (4 or 16)
            LOADCI(B, ci + 1);                  // prefetch odd ci
            FMACI(A, ci);                       // 432/108 FMAs cover latency
            if (ci + 2 < CIN) LOADCI(A, ci + 2);// prefetch next even ci
            FMACI(B, ci + 1);
        }
    }
#undef LOADCI
#undef FMACI

    if constexpr (PADOUT) {
        float* yb = y + (size_t)b * COUTT * zcs + (size_t)cog * COUTS * zcs
                  + (size_t)(d + 1) * zhs + (size_t)(h + 1) * WZ + wcol;
#pragma unroll
        for (int co = 0; co < COUTS; ++co) {
            float4 v;
            v.x = acc[co][0]; v.y = acc[co][1]; v.z = acc[co][2]; v.w = acc[co][3];
            if (RELU) {
                v.x = fmaxf(v.x, 0.f); v.y = fmaxf(v.y, 0.f);
                v.z = fmaxf(v.z, 0.f); v.w = fmaxf(v.w, 0.f);
            }
            *reinterpret_cast<float4*>(yb + (size_t)co * zcs) = v;
        }
    } else {
        const int chs = D * H * W;
        float* yb = y + (size_t)b * COUTT * chs + (size_t)cog * COUTS * chs
                  + (d * H + h) * W + sw * 4;
#pragma unroll
        for (int co = 0; co < COUTS; ++co) {
            float4 v;
            v.x = acc[co][0]; v.y = acc[co][1]; v.z = acc[co][2]; v.w = acc[co][3];
            if (RELU) {
                v.x = fmaxf(v.x, 0.f); v.y = fmaxf(v.y, 0.f);
                v.z = fmaxf(v.z, 0.f); v.w = fmaxf(v.w, 0.f);
            }
            *reinterpret_cast<float4*>(yb + (size_t)co * chs) = v;
        }
    }
}

// ---------------- softargmin disparity regression ----------------
__global__ __launch_bounds__(256) void dispreg_k(const float* __restrict__ cost,
                                                 float* __restrict__ dsm,
                                                 int total, int D, int HW,
                                                 float dstart, float scale) {
    int idx = blockIdx.x * 256 + threadIdx.x;
    if (idx >= total) return;
    int hw = idx % HW; int b = idx / HW;
    const float* c = cost + b * D * HW + hw;
    float m = -1e30f;
    for (int d = 0; d < D; ++d) m = fmaxf(m, -c[d * HW]);
    float s = 0.f, ws = 0.f;
    for (int d = 0; d < D; ++d) {
        float e = expf(-c[d * HW] - m);
        s += e;
        ws = fmaf(e, dstart + (float)d, ws);
    }
    dsm[idx] = ws / s * scale;
}

// ---------------- bilinear upsample + optional residual + optional depth ----------------
__global__ __launch_bounds__(256) void upsample_add_k(const float* __restrict__ s,
                                                      int sh, int sw,
                                                      const float* __restrict__ prev,
                                                      float* __restrict__ out,
                                                      float* __restrict__ dep) {
    int idx = blockIdx.x * 256 + threadIdx.x;
    if (idx >= NPIX) return;
    int x = idx % FULL_W; int t = idx / FULL_W;
    int y = t % FULL_H; int b = t / FULL_H;
    float fy = (y + 0.5f) * ((float)sh / FULL_H) - 0.5f;
    float fx = (x + 0.5f) * ((float)sw / FULL_W) - 0.5f;
    int y0 = (int)floorf(fy); float wy = fy - (float)y0;
    int x0 = (int)floorf(fx); float wx = fx - (float)x0;
    int y0c = min(max(y0, 0), sh - 1), y1c = min(max(y0 + 1, 0), sh - 1);
    int x0c = min(max(x0, 0), sw - 1), x1c = min(max(x0 + 1, 0), sw - 1);
    const float* sb = s + b * sh * sw;
    float v00 = sb[y0c * sw + x0c], v01 = sb[y0c * sw + x1c];
    float v10 = sb[y1c * sw + x0c], v11 = sb[y1c * sw + x1c];
    float v = (1.f - wy) * ((1.f - wx) * v00 + wx * v01) +
              wy        * ((1.f - wx) * v10 + wx * v11);
    if (prev) v += prev[idx];
    out[idx] = v;
    if (dep) {
        float p = fabsf(v);
        float d = 64.f / p;                 // BASELINE*FOCAL
        if (isnan(d)) d = 100.f;
        d = fminf(fmaxf(d, 0.1f), 100.f);
        dep[idx] = d;
    }
}

// ---------------- antialiased triangle downsample + scale ----------------
__global__ __launch_bounds__(256) void wflow_k(const float* __restrict__ pred,
                                               float* __restrict__ wf,
                                               int oh, int ow, int f, float scale) {
    int idx = blockIdx.x * 256 + threadIdx.x;
    int total = NB * oh * ow;
    if (idx >= total) return;
    int ox = idx % ow; int t = idx / ow;
    int oy = t % oh; int b = t / oh;
    float ff = (float)f, invf = 1.f / (float)f;
    float cy = (oy + 0.5f) * ff - 0.5f;
    float cx = (ox + 0.5f) * ff - 0.5f;
    int ylo = max((int)ceilf(cy - ff), 0);
    int yhi = min((int)floorf(cy + ff), FULL_H - 1);
    int xlo = max((int)ceilf(cx - ff), 0);
    int xhi = min((int)floorf(cx + ff), FULL_W - 1);
    const float* pb = pred + b * FULL_H * FULL_W;
    float acc = 0.f, wys = 0.f, wxs = 0.f;
    for (int iy = ylo; iy <= yhi; ++iy) {
        float wy = 1.f - fabsf((float)iy - cy) * invf;
        wys += wy;
        float rowacc = 0.f;
        const float* row = pb + iy * FULL_W;
        for (int ix = xlo; ix <= xhi; ++ix) {
            float wx = 1.f - fabsf((float)ix - cx) * invf;
            rowacc = fmaf(wx, row[ix], rowacc);
        }
        acc = fmaf(wy, rowacc, acc);
    }
    for (int ix = xlo; ix <= xhi; ++ix) wxs += 1.f - fabsf((float)ix - cx) * invf;
    wf[idx] = acc / (wys * wxs) * scale;
}

static inline dim3 g(int n) { return dim3((n + 255) / 256); }
static inline dim3 gs(int nstrips, int nspl) { return dim3(((nstrips + 255) / 256) * nspl); }

extern "C" void kernel_launch(void* const* d_in, const int* in_sizes, int n_in,
                              void* d_out, int out_size, void* d_ws, size_t ws_size,
                              hipStream_t stream) {
    const float* f_l0  = (const float*)d_in[0];
    const float* f_r0  = (const float*)d_in[1];
    const float* f_l1  = (const float*)d_in[2];
    const float* f_r1  = (const float*)d_in[3];
    const float* f_l2  = (const float*)d_in[4];
    const float* f_r2  = (const float*)d_in[5];
    const float* w_in0  = (const float*)d_in[6];
    const float* w_mid0 = (const float*)d_in[7];
    const float* w_out0 = (const float*)d_in[8];
    const float* w_in1  = (const float*)d_in[9];
    const float* w_mid1 = (const float*)d_in[10];
    const float* w_out1 = (const float*)d_in[11];
    const float* w_in2  = (const float*)d_in[12];
    const float* w_mid2 = (const float*)d_in[13];
    const float* w_out2 = (const float*)d_in[14];

    float* out   = (float*)d_out;
    float* pred0 = out;
    float* pred1 = out + NPIX;
    float* pred2 = out + 2 * NPIX;
    float* depth = out + 3 * NPIX;

    float* ws = (float*)d_ws;
    float* P    = ws;               // padded ping (max 9,551,360 floats)
    float* Q    = ws + 9551360;     // padded pong
    float* CP   = ws + 19102720;    // padded cost input (max 2,387,840)
    float* CO   = ws + 21490560;    // unpadded conv output (max 1,638,400)
    float* dsm  = ws + 23128960;    // 327,680
    float* wfl  = ws + 23456640;    // 327,680  (end ~95.1 MB)

    dim3 blk(256);

    // ---------------- stage 0 ----------------
    {
        const int D = 12, H = 32, W = 80, DZ = 14, HZ = 34, WZ = 88;
        const size_t pcn = (size_t)NB * 16 * DZ * HZ * WZ;   // 5,361,664
        const size_t cpn = (size_t)NB * DZ * HZ * WZ;        //   335,104
        hipMemsetAsync(P,  0, pcn * 4, stream);
        hipMemsetAsync(Q,  0, pcn * 4, stream);
        hipMemsetAsync(CP, 0, cpn * 4, stream);
        const int total = NB * D * H * W;                    // 245,760
        cost0p_k<<<g(total), blk, 0, stream>>>(f_l0, f_r0, CP);
        int ns4 = total / 4;                                 // 61,440
        convp4_k<1, 16, 16, true, true><<<gs(ns4, 1), blk, 0, stream>>>(CP, w_in0, P, D, H, W, DZ, HZ, WZ, ns4);
        const float* src = P; float* dst = Q;
        for (int k = 0; k < 4; ++k) {
            convp4_k<16, 16, 8, true, true><<<gs(ns4, 2), blk, 0, stream>>>(src, w_mid0 + k * 6912, dst, D, H, W, DZ, HZ, WZ, ns4);
            const float* nsrc = dst; dst = (float*)src; src = nsrc;
        }
        convp4_k<16, 1, 1, false, false><<<gs(ns4, 1), blk, 0, stream>>>(src, w_out0, CO, D, H, W, DZ, HZ, WZ, ns4);
        dispreg_k<<<g(NB * H * W), blk, 0, stream>>>(CO, dsm, NB * H * W, D, H * W, 0.f, 16.f);
        upsample_add_k<<<g(NPIX), blk, 0, stream>>>(dsm, H, W, nullptr, pred0, depth);
    }

    // ---------------- stage 1 ----------------
    {
        const int D = 5, H = 64, W = 160, DZ = 7, HZ = 66, WZ = 168;
        const size_t pcn = (size_t)NB * 4 * DZ * HZ * WZ;    // 2,483,712
        const size_t cpn = (size_t)NB * DZ * HZ * WZ;        //   620,928
        hipMemsetAsync(P,  0, pcn * 4, stream);
        hipMemsetAsync(Q,  0, pcn * 4, stream);
        hipMemsetAsync(CP, 0, cpn * 4, stream);
        const int total = NB * D * H * W;                    // 409,600
        wflow_k<<<g(NB * H * W), blk, 0, stream>>>(pred0, wfl, H, W, 8, 0.125f);
        costresp_k<<<g(total), blk, 0, stream>>>(f_l1, f_r1, wfl, CP, H, W, HZ, WZ);
        int ns4 = total / 4;                                 // 102,400
        convp4_k<1, 4, 4, true, true><<<gs(ns4, 1), blk, 0, stream>>>(CP, w_in1, P, D, H, W, DZ, HZ, WZ, ns4);
        const float* src = P; float* dst = Q;
        for (int k = 0; k < 4; ++k) {
            convp4_k<4, 4, 4, true, true><<<gs(ns4, 1), blk, 0, stream>>>(src, w_mid1 + k * 432, dst, D, H, W, DZ, HZ, WZ, ns4);
            const float* nsrc = dst; dst = (float*)src; src = nsrc;
        }
        convp4_k<4, 1, 1, false, false><<<gs(ns4, 1), blk, 0, stream>>>(src, w_out1, CO, D, H, W, DZ, HZ, WZ, ns4);
        dispreg_k<<<g(NB * H * W), blk, 0, stream>>>(CO, dsm, NB * H * W, D, H * W, -2.f, 8.f);
        upsample_add_k<<<g(NPIX), blk, 0, stream>>>(dsm, H, W, pred0, pred1, nullptr);
    }

    // ---------------- stage 2 ----------------
    {
        const int D = 5, H = 128, W = 320, DZ = 7, HZ = 130, WZ = 328;
        const size_t pcn = (size_t)NB * 4 * DZ * HZ * WZ;    // 9,551,360
        const size_t cpn = (size_t)NB * DZ * HZ * WZ;        // 2,387,840
        hipMemsetAsync(P,  0, pcn * 4, stream);
        hipMemsetAsync(Q,  0, pcn * 4, stream);
        hipMemsetAsync(CP, 0, cpn * 4, stream);
        const int total = NB * D * H * W;                    // 1,638,400
        wflow_k<<<g(NB * H * W), blk, 0, stream>>>(pred1, wfl, H, W, 4, 0.25f);
        costresp_k<<<g(total), blk, 0, stream>>>(f_l2, f_r2, wfl, CP, H, W, HZ, WZ);
        int ns4 = total / 4;                                 // 409,600
        convp4_k<1, 4, 4, true, true><<<gs(ns4, 1), blk, 0, stream>>>(CP, w_in2, P, D, H, W, DZ, HZ, WZ, ns4);
        const float* src = P; float* dst = Q;
        for (int k = 0; k < 4; ++k) {
            convp4_k<4, 4, 4, true, true><<<gs(ns4, 1), blk, 0, stream>>>(src, w_mid2 + k * 432, dst, D, H, W, DZ, HZ, WZ, ns4);
            const float* nsrc = dst; dst = (float*)src; src = nsrc;
        }
        convp4_k<4, 1, 1, false, false><<<gs(ns4, 1), blk, 0, stream>>>(src, w_out2, CO, D, H, W, DZ, HZ, WZ, ns4);
        dispreg_k<<<g(NB * H * W), blk, 0, stream>>>(CO, dsm, NB * H * W, D, H * W, -2.f, 4.f);
        upsample_add_k<<<g(NPIX), blk, 0, stream>>>(dsm, H, W, pred1, pred2, nullptr);
    }
}